// Round 1
// baseline (2537.142 us; speedup 1.0000x reference)
//
#include <hip/hip_runtime.h>

// ---- sizes (fixed by the problem) ----
#define Bsz 64
#define Tsz 64
#define Vsz 32000
#define DEsz 512
#define DDsz 1024
#define DCsz 512
#define DIN 1024     // DE+DC
#define G3 3072      // 3*DD

typedef unsigned short u16;
typedef __attribute__((ext_vector_type(8))) __bf16 bf16x8;
typedef __attribute__((ext_vector_type(4))) float f32x4;

__device__ __forceinline__ u16 f2bf(float f) {
    union { float f; unsigned int u; } v; v.f = f;
    unsigned int r = v.u + 0x7fffu + ((v.u >> 16) & 1u);  // RNE
    return (u16)(r >> 16);
}

// ---------- f32 -> bf16 bulk convert ----------
__global__ void f32_to_bf16(const float* __restrict__ src, u16* __restrict__ dst, long n) {
    long i = ((long)blockIdx.x * blockDim.x + threadIdx.x) * 4;
    if (i + 3 < n) {
        float4 v = *(const float4*)&src[i];
        dst[i + 0] = f2bf(v.x);
        dst[i + 1] = f2bf(v.y);
        dst[i + 2] = f2bf(v.z);
        dst[i + 3] = f2bf(v.w);
    }
}

// ---------- build X = concat(emb[token], context) as bf16, row = t*B + b ----------
__global__ void build_x(const float* __restrict__ emb, const float* __restrict__ ctx,
                        const int* __restrict__ labels, const int* __restrict__ bos,
                        u16* __restrict__ X) {
    int i = blockIdx.x;            // 0..4095
    int t = i >> 6;                // /B
    int b = i & 63;
    int tok = (t == 0) ? *bos : labels[b * Tsz + (t - 1)];
    const float* s0 = emb + (long)tok * DEsz;
    const float* s1 = ctx + (long)b * DCsz;
    u16* dst = X + (long)i * DIN;
    for (int c = threadIdx.x; c < DEsz; c += blockDim.x) {
        dst[c]         = f2bf(s0[c]);
        dst[DEsz + c]  = f2bf(s1[c]);
    }
}

// ---------- h0 = broadcast(init) ----------
__global__ void init_h(const float* __restrict__ init, u16* __restrict__ hbf,
                       float* __restrict__ hf) {
    int c = blockIdx.x * blockDim.x + threadIdx.x;   // 0..65535
    float v = init[c & (DDsz - 1)];
    hbf[c] = f2bf(v);
    hf[c]  = v;
}

// ---------- C = A(MxK bf16 rows) . B(NxK bf16 rows)^T + bias, fp32 out ----------
// BM=BN=64, BK=32; 256 threads = 4 waves; wave w owns rows [w*16, w*16+16) x all 64 cols.
template<bool TRANS_OUT>
__global__ __launch_bounds__(256) void gemm_bt(
    const u16* __restrict__ A, const u16* __restrict__ Bm,
    const float* __restrict__ bias, float* __restrict__ C,
    int M, int N, int K)
{
    __shared__ __align__(16) u16 As[64][40];
    __shared__ __align__(16) u16 Bs[64][40];
    const int tid  = threadIdx.x;
    const int wave = tid >> 6;
    const int lane = tid & 63;
    const int bm = blockIdx.y * 64;
    const int bn = blockIdx.x * 64;
    const int lr = tid >> 2;          // stage row 0..63
    const int lc = (tid & 3) * 8;     // stage col 0/8/16/24
    const long abase = (long)(bm + lr) * K + lc;
    const long bbase = (long)(bn + lr) * K + lc;
    const int fr = lane & 15;
    const int kk = (lane >> 4) * 8;

    f32x4 acc[4];
    #pragma unroll
    for (int n = 0; n < 4; ++n) acc[n] = f32x4{0.f, 0.f, 0.f, 0.f};

    for (int k0 = 0; k0 < K; k0 += 32) {
        *(bf16x8*)&As[lr][lc] = *(const bf16x8*)&A[abase + k0];
        *(bf16x8*)&Bs[lr][lc] = *(const bf16x8*)&Bm[bbase + k0];
        __syncthreads();
        bf16x8 af = *(const bf16x8*)&As[wave * 16 + fr][kk];
        #pragma unroll
        for (int n = 0; n < 4; ++n) {
            bf16x8 bf = *(const bf16x8*)&Bs[n * 16 + fr][kk];
            acc[n] = __builtin_amdgcn_mfma_f32_16x16x32_bf16(af, bf, acc[n], 0, 0, 0);
        }
        __syncthreads();
    }

    const int r0 = (lane >> 4) * 4;
    #pragma unroll
    for (int n = 0; n < 4; ++n) {
        int col = bn + n * 16 + fr;
        float bv = bias[col];
        #pragma unroll
        for (int j = 0; j < 4; ++j) {
            int row = bm + wave * 16 + r0 + j;
            long oi;
            if (TRANS_OUT) {
                int t = row >> 6;            // row = t*B + b   (B=64)
                int b = row & 63;
                oi = ((long)b * Tsz + t) * (long)N + col;   // out[b][t][v]
            } else {
                oi = (long)row * N + col;
            }
            C[oi] = acc[n][j] + bv;
        }
    }
}

// ---------- one GRU step: gh = h @ W_hh^T, gates fused, h updated ----------
// grid 32 blocks (each owns 32 hidden cols), 256 threads = 4 waves (each owns 16 batch rows)
__global__ __launch_bounds__(256) void gru_step(
    const u16* __restrict__ hprev_bf,    // [64][1024]
    const float* __restrict__ hprev_f,   // [64][1024]
    const u16* __restrict__ Whh,         // [3072][1024] bf16
    const float* __restrict__ bhh,       // [3072]
    const float* __restrict__ gi,        // [4096][3072]
    int t,
    u16* __restrict__ hnew_bf,
    float* __restrict__ hnew_f)
{
    __shared__ __align__(16) u16 Hs[64][40];
    __shared__ __align__(16) u16 Ws[96][40];
    const int tid  = threadIdx.x;
    const int wave = tid >> 6;
    const int lane = tid & 63;
    const int c0 = blockIdx.x * 32;
    const int fr = lane & 15;
    const int kk = (lane >> 4) * 8;

    f32x4 acc[6];
    #pragma unroll
    for (int n = 0; n < 6; ++n) acc[n] = f32x4{0.f, 0.f, 0.f, 0.f};

    const int hr = tid >> 2;
    const int hc = (tid & 3) * 8;

    for (int k0 = 0; k0 < DDsz; k0 += 32) {
        *(bf16x8*)&Hs[hr][hc] = *(const bf16x8*)&hprev_bf[(long)hr * DDsz + k0 + hc];
        for (int i = tid; i < 96 * 4; i += 256) {
            int r = i >> 2;
            int c = (i & 3) * 8;
            int g = r >> 5;                        // gate 0..2
            long wr = (long)g * DDsz + c0 + (r & 31);
            *(bf16x8*)&Ws[r][c] = *(const bf16x8*)&Whh[wr * DDsz + k0 + c];
        }
        __syncthreads();
        bf16x8 hf = *(const bf16x8*)&Hs[wave * 16 + fr][kk];
        #pragma unroll
        for (int n = 0; n < 6; ++n) {
            bf16x8 wf = *(const bf16x8*)&Ws[n * 16 + fr][kk];
            acc[n] = __builtin_amdgcn_mfma_f32_16x16x32_bf16(hf, wf, acc[n], 0, 0, 0);
        }
        __syncthreads();
    }

    // acc[g*2+q][j]: gate g, col c0+q*16+(lane&15), batch row wave*16+(lane>>4)*4+j
    const int r0 = (lane >> 4) * 4;
    #pragma unroll
    for (int q = 0; q < 2; ++q) {
        int c = c0 + q * 16 + fr;
        float bR = bhh[c];
        float bZ = bhh[DDsz + c];
        float bN = bhh[2 * DDsz + c];
        #pragma unroll
        for (int j = 0; j < 4; ++j) {
            int b = wave * 16 + r0 + j;
            long gib = ((long)t * Bsz + b) * G3;
            float i_r = gi[gib + c];
            float i_z = gi[gib + DDsz + c];
            float i_n = gi[gib + 2 * DDsz + c];
            float r = 1.f / (1.f + expf(-(i_r + acc[q][j] + bR)));
            float z = 1.f / (1.f + expf(-(i_z + acc[2 + q][j] + bZ)));
            float n = tanhf(i_n + r * (acc[4 + q][j] + bN));
            float hp = hprev_f[(long)b * DDsz + c];
            float h = (1.f - z) * n + z * hp;
            hnew_f[(long)b * DDsz + c] = h;
            hnew_bf[(long)b * DDsz + c] = f2bf(h);
        }
    }
}

extern "C" void kernel_launch(void* const* d_in, const int* in_sizes, int n_in,
                              void* d_out, int out_size, void* d_ws, size_t ws_size,
                              hipStream_t stream) {
    const float* ctx    = (const float*)d_in[0];
    const int*   labels = (const int*)  d_in[1];
    const float* emb    = (const float*)d_in[2];
    const float* W_ih   = (const float*)d_in[3];
    const float* b_ih   = (const float*)d_in[4];
    const float* W_hh   = (const float*)d_in[5];
    const float* b_hh   = (const float*)d_in[6];
    const float* initp  = (const float*)d_in[7];
    const float* W_out  = (const float*)d_in[8];
    const float* b_out  = (const float*)d_in[9];
    const int*   bos    = (const int*)  d_in[10];
    float* out = (float*)d_out;

    char* ws = (char*)d_ws;
    u16*   Xbf    = (u16*)  (ws + 0L);            //  8,388,608  (4096x1024 bf16)
    float* gi     = (float*)(ws + 8388608L);      // 50,331,648  (4096x3072 f32)
    u16*   hst    = (u16*)  (ws + 58720256L);     //  8,519,680  (65x64x1024 bf16)
    float* hf     = (float*)(ws + 67239936L);     // 17,039,360  (65x64x1024 f32)
    u16*   Wih_b  = (u16*)  (ws + 84279296L);     //  6,291,456
    u16*   Whh_b  = (u16*)  (ws + 90570752L);     //  6,291,456
    u16*   Wout_b = (u16*)  (ws + 96862208L);     // 65,536,000  -> end 162,398,208

    long n1 = (long)G3 * DIN;          // 3,145,728
    long n2 = (long)Vsz * DDsz;        // 32,768,000
    f32_to_bf16<<<(unsigned)(n1 / 4 / 256), 256, 0, stream>>>(W_ih, Wih_b, n1);
    f32_to_bf16<<<(unsigned)(n1 / 4 / 256), 256, 0, stream>>>(W_hh, Whh_b, n1);
    f32_to_bf16<<<(unsigned)(n2 / 4 / 256), 256, 0, stream>>>(W_out, Wout_b, n2);

    build_x<<<Bsz * Tsz, 128, 0, stream>>>(emb, ctx, labels, bos, Xbf);
    init_h<<<(Bsz * DDsz) / 256, 256, 0, stream>>>(initp, hst, hf);

    // gi = X @ W_ih^T + b_ih   (4096 x 3072)
    {
        dim3 g(G3 / 64, (Bsz * Tsz) / 64);
        gemm_bt<false><<<g, 256, 0, stream>>>(Xbf, Wih_b, b_ih, gi, Bsz * Tsz, G3, DIN);
    }

    // 64 recurrent steps
    for (int t = 0; t < Tsz; ++t) {
        gru_step<<<DDsz / 32, 256, 0, stream>>>(
            hst + (long)t * Bsz * DDsz, hf + (long)t * Bsz * DDsz,
            Whh_b, b_hh, gi, t,
            hst + (long)(t + 1) * Bsz * DDsz, hf + (long)(t + 1) * Bsz * DDsz);
    }

    // logits = states @ W_out^T + b_out  -> out[b][t][v]
    {
        dim3 g(Vsz / 64, (Bsz * Tsz) / 64);
        gemm_bt<true><<<g, 256, 0, stream>>>(hst + (long)Bsz * DDsz, Wout_b, b_out, out,
                                             Bsz * Tsz, Vsz, DDsz);
    }
}

// Round 2
// 1673.954 us; speedup vs baseline: 1.5157x; 1.5157x over previous
//
#include <hip/hip_runtime.h>

// ---- sizes (fixed by the problem) ----
#define Bsz 64
#define Tsz 64
#define Vsz 32000
#define DEsz 512
#define DDsz 1024
#define DCsz 512
#define DIN 1024     // DE+DC
#define G3 3072      // 3*DD

typedef unsigned short u16;
typedef __attribute__((ext_vector_type(8))) __bf16 bf16x8;
typedef __attribute__((ext_vector_type(4))) float f32x4;

__device__ __forceinline__ u16 f2bf(float f) {
    union { float f; unsigned int u; } v; v.f = f;
    unsigned int r = v.u + 0x7fffu + ((v.u >> 16) & 1u);  // RNE
    return (u16)(r >> 16);
}

__device__ __forceinline__ void gload_lds16(const u16* g, u16* l) {
    __builtin_amdgcn_global_load_lds(
        (const __attribute__((address_space(1))) void*)g,
        (__attribute__((address_space(3))) void*)l, 16, 0, 0);
}

// ---------- f32 -> bf16 bulk convert ----------
__global__ void f32_to_bf16(const float* __restrict__ src, u16* __restrict__ dst, long n) {
    long i = ((long)blockIdx.x * blockDim.x + threadIdx.x) * 4;
    if (i + 3 < n) {
        float4 v = *(const float4*)&src[i];
        dst[i + 0] = f2bf(v.x);
        dst[i + 1] = f2bf(v.y);
        dst[i + 2] = f2bf(v.z);
        dst[i + 3] = f2bf(v.w);
    }
}

// ---------- build X = concat(emb[token], context) as bf16, row = t*B + b ----------
__global__ void build_x(const float* __restrict__ emb, const float* __restrict__ ctx,
                        const int* __restrict__ labels, const int* __restrict__ bos,
                        u16* __restrict__ X) {
    int i = blockIdx.x;            // 0..4095
    int t = i >> 6;
    int b = i & 63;
    int tok = (t == 0) ? *bos : labels[b * Tsz + (t - 1)];
    const float* s0 = emb + (long)tok * DEsz;
    const float* s1 = ctx + (long)b * DCsz;
    u16* dst = X + (long)i * DIN;
    for (int c = threadIdx.x; c < DEsz; c += blockDim.x) {
        dst[c]        = f2bf(s0[c]);
        dst[DEsz + c] = f2bf(s1[c]);
    }
}

// ---------- h0 = broadcast(init) bf16 ----------
__global__ void init_h(const float* __restrict__ init, u16* __restrict__ hbf) {
    int c = blockIdx.x * blockDim.x + threadIdx.x;   // 0..65535
    hbf[c] = f2bf(init[c & (DDsz - 1)]);
}

// ---------- 128x128 m97-style GEMM: C = A . B^T + bias ----------
// A: [M][K] bf16 rows, B: [N][K] bf16 rows, C fp32. 256 thr = 4 waves (2x2 of 64x64).
// flat grid, bm-fastest (B-panel reuse) + XCD swizzle.
template<bool TRANS_OUT>
__global__ __launch_bounds__(256) void gemm128(
    const u16* __restrict__ A, const u16* __restrict__ Bm,
    const float* __restrict__ bias, float* __restrict__ C,
    int N, int K, int mblk)
{
    __shared__ __align__(16) u16 As[128 * 32];
    __shared__ __align__(16) u16 Bs[128 * 32];
    const int tid  = threadIdx.x;
    const int wave = tid >> 6;
    const int lane = tid & 63;
    const int wm = wave >> 1, wn = wave & 1;

    int nwg = gridDim.x;
    int wg  = blockIdx.x;
    int cpx = nwg >> 3;                      // nwg % 8 == 0 by construction
    wg = (wg & 7) * cpx + (wg >> 3);         // XCD-aware swizzle (bijective)
    const int bm = (wg % mblk) * 128;        // bm fastest -> consecutive wgs share B panel
    const int bn = (wg / mblk) * 128;

    const int sr = tid >> 2;                 // stage row 0..63
    const int sc = (tid & 3) * 8;            // stage col 0/8/16/24
    const u16* ga0 = A  + (long)(bm + sr) * K + sc;
    const u16* ga1 = A  + (long)(bm + 64 + sr) * K + sc;
    const u16* gb0 = Bm + (long)(bn + sr) * K + sc;
    const u16* gb1 = Bm + (long)(bn + 64 + sr) * K + sc;
    u16* la0 = As + tid * 8;
    u16* la1 = As + 2048 + tid * 8;
    u16* lb0 = Bs + tid * 8;
    u16* lb1 = Bs + 2048 + tid * 8;

    const int fr = lane & 15;
    const int kh = (lane >> 4) * 8;

    f32x4 acc[4][4];
    #pragma unroll
    for (int i = 0; i < 4; ++i)
        #pragma unroll
        for (int j = 0; j < 4; ++j) acc[i][j] = f32x4{0.f, 0.f, 0.f, 0.f};

    for (int k0 = 0; k0 < K; k0 += 32) {
        gload_lds16(ga0 + k0, la0);
        gload_lds16(ga1 + k0, la1);
        gload_lds16(gb0 + k0, lb0);
        gload_lds16(gb1 + k0, lb1);
        __syncthreads();
        bf16x8 af[4], bf[4];
        #pragma unroll
        for (int mi = 0; mi < 4; ++mi)
            af[mi] = *(const bf16x8*)&As[(wm * 64 + mi * 16 + fr) * 32 + kh];
        #pragma unroll
        for (int ni = 0; ni < 4; ++ni)
            bf[ni] = *(const bf16x8*)&Bs[(wn * 64 + ni * 16 + fr) * 32 + kh];
        #pragma unroll
        for (int mi = 0; mi < 4; ++mi)
            #pragma unroll
            for (int ni = 0; ni < 4; ++ni)
                acc[mi][ni] = __builtin_amdgcn_mfma_f32_16x16x32_bf16(af[mi], bf[ni], acc[mi][ni], 0, 0, 0);
        __syncthreads();
    }

    const int r0 = (lane >> 4) * 4;
    #pragma unroll
    for (int mi = 0; mi < 4; ++mi) {
        #pragma unroll
        for (int ni = 0; ni < 4; ++ni) {
            int col = bn + wn * 64 + ni * 16 + fr;
            float bv = bias[col];
            #pragma unroll
            for (int j = 0; j < 4; ++j) {
                int row = bm + wm * 64 + mi * 16 + r0 + j;
                long oi;
                if (TRANS_OUT) {
                    oi = ((long)(row & 63) * Tsz + (row >> 6)) * (long)N + col;  // out[b][t][v]
                } else {
                    oi = (long)row * N + col;
                }
                C[oi] = acc[mi][ni][j] + bv;
            }
        }
    }
}

// ---------- device-scope grid barrier ----------
__device__ __forceinline__ void grid_bar(int* cnt, int* gen, int nb) {
    __threadfence();                 // release this thread's h stores
    __syncthreads();
    if (threadIdx.x == 0) {
        int g = __hip_atomic_load(gen, __ATOMIC_RELAXED, __HIP_MEMORY_SCOPE_AGENT);
        int a = __hip_atomic_fetch_add(cnt, 1, __ATOMIC_ACQ_REL, __HIP_MEMORY_SCOPE_AGENT);
        if (a == nb - 1) {
            __hip_atomic_store(cnt, 0, __ATOMIC_RELAXED, __HIP_MEMORY_SCOPE_AGENT);
            __hip_atomic_fetch_add(gen, 1, __ATOMIC_RELEASE, __HIP_MEMORY_SCOPE_AGENT);
        } else {
            while (__hip_atomic_load(gen, __ATOMIC_ACQUIRE, __HIP_MEMORY_SCOPE_AGENT) == g)
                __builtin_amdgcn_s_sleep(1);
        }
    }
    __syncthreads();
    __threadfence();                 // acquire: invalidate before reading remote h
}

// ---------- persistent GRU: all 64 steps in one launch ----------
// 64 blocks x 128 thr (2 waves). Block owns 16 hidden cols x 3 gates.
// W slice (48x1024, pad 8) LDS-resident across all steps; h carry in f32 regs.
__global__ __launch_bounds__(128) void gru_persist(
    const u16* __restrict__ Whh,     // [3072][1024] bf16
    const float* __restrict__ bhh,   // [3072]
    const float* __restrict__ gi,    // [4096][3072] f32
    const float* __restrict__ initp, // [1024]
    u16* __restrict__ hst,           // [65][64][1024] bf16
    int* __restrict__ bar)           // {cnt, gen} zeroed
{
    __shared__ __align__(16) u16 Wl[48 * 1032];   // +8 pad: 2-way (free) LDS reads
    const int tid  = threadIdx.x;
    const int w    = tid >> 6;       // wave 0/1 -> batch half
    const int lane = tid & 63;
    const int c0   = blockIdx.x * 16;
    const int fr   = lane & 15;
    const int kh   = (lane >> 4) * 8;
    const int r0   = (lane >> 4) * 4;

    // preload W slice: LDS row g*16+i  <-  Whh[g*1024 + c0 + i]
    for (int ch = tid; ch < 48 * 128; ch += 128) {
        int r  = ch >> 7;
        int cc = (ch & 127) * 8;
        int g  = r >> 4, i = r & 15;
        *(bf16x8*)&Wl[r * 1032 + cc] =
            *(const bf16x8*)&Whh[((long)g * DDsz + c0 + i) * DDsz + cc];
    }
    __syncthreads();

    float hc[2][4];
    {
        float v = initp[c0 + fr];
        #pragma unroll
        for (int mt = 0; mt < 2; ++mt)
            #pragma unroll
            for (int j = 0; j < 4; ++j) hc[mt][j] = v;
    }
    const float bR = bhh[c0 + fr];
    const float bZ = bhh[DDsz + c0 + fr];
    const float bN = bhh[2 * DDsz + c0 + fr];

    for (int t = 0; t < Tsz; ++t) {
        // prefetch gi terms (independent of K-loop)
        float gir[2][4], giz[2][4], gin_[2][4];
        #pragma unroll
        for (int mt = 0; mt < 2; ++mt)
            #pragma unroll
            for (int j = 0; j < 4; ++j) {
                long gib = ((long)t * Bsz + w * 32 + mt * 16 + r0 + j) * G3 + c0 + fr;
                gir[mt][j]  = gi[gib];
                giz[mt][j]  = gi[gib + DDsz];
                gin_[mt][j] = gi[gib + 2 * DDsz];
            }

        f32x4 acc[3][2];
        #pragma unroll
        for (int g = 0; g < 3; ++g)
            #pragma unroll
            for (int mt = 0; mt < 2; ++mt) acc[g][mt] = f32x4{0.f, 0.f, 0.f, 0.f};

        const u16* hrow = hst + (long)t * Bsz * DDsz;
        #pragma unroll 4
        for (int k0 = 0; k0 < DDsz; k0 += 32) {
            bf16x8 a0 = *(const bf16x8*)&hrow[(w * 32 + fr) * DDsz + k0 + kh];
            bf16x8 a1 = *(const bf16x8*)&hrow[(w * 32 + 16 + fr) * DDsz + k0 + kh];
            bf16x8 wr_ = *(const bf16x8*)&Wl[(0  + fr) * 1032 + k0 + kh];
            bf16x8 wz_ = *(const bf16x8*)&Wl[(16 + fr) * 1032 + k0 + kh];
            bf16x8 wn_ = *(const bf16x8*)&Wl[(32 + fr) * 1032 + k0 + kh];
            acc[0][0] = __builtin_amdgcn_mfma_f32_16x16x32_bf16(a0, wr_, acc[0][0], 0, 0, 0);
            acc[0][1] = __builtin_amdgcn_mfma_f32_16x16x32_bf16(a1, wr_, acc[0][1], 0, 0, 0);
            acc[1][0] = __builtin_amdgcn_mfma_f32_16x16x32_bf16(a0, wz_, acc[1][0], 0, 0, 0);
            acc[1][1] = __builtin_amdgcn_mfma_f32_16x16x32_bf16(a1, wz_, acc[1][1], 0, 0, 0);
            acc[2][0] = __builtin_amdgcn_mfma_f32_16x16x32_bf16(a0, wn_, acc[2][0], 0, 0, 0);
            acc[2][1] = __builtin_amdgcn_mfma_f32_16x16x32_bf16(a1, wn_, acc[2][1], 0, 0, 0);
        }

        u16* hout = hst + (long)(t + 1) * Bsz * DDsz;
        #pragma unroll
        for (int mt = 0; mt < 2; ++mt) {
            int bb = w * 32 + mt * 16 + r0;
            #pragma unroll
            for (int j = 0; j < 4; ++j) {
                float r = 1.f / (1.f + expf(-(gir[mt][j] + acc[0][mt][j] + bR)));
                float z = 1.f / (1.f + expf(-(giz[mt][j] + acc[1][mt][j] + bZ)));
                float n = tanhf(gin_[mt][j] + r * (acc[2][mt][j] + bN));
                float h = (1.f - z) * n + z * hc[mt][j];
                hc[mt][j] = h;
                hout[(long)(bb + j) * DDsz + c0 + fr] = f2bf(h);
            }
        }
        grid_bar(bar, bar + 1, gridDim.x);
    }
}

extern "C" void kernel_launch(void* const* d_in, const int* in_sizes, int n_in,
                              void* d_out, int out_size, void* d_ws, size_t ws_size,
                              hipStream_t stream) {
    const float* ctx    = (const float*)d_in[0];
    const int*   labels = (const int*)  d_in[1];
    const float* emb    = (const float*)d_in[2];
    const float* W_ih   = (const float*)d_in[3];
    const float* b_ih   = (const float*)d_in[4];
    const float* W_hh   = (const float*)d_in[5];
    const float* b_hh   = (const float*)d_in[6];
    const float* initp  = (const float*)d_in[7];
    const float* W_out  = (const float*)d_in[8];
    const float* b_out  = (const float*)d_in[9];
    const int*   bos    = (const int*)  d_in[10];
    float* out = (float*)d_out;

    char* ws = (char*)d_ws;
    u16*   Xbf    = (u16*)  (ws + 0L);            //  8,388,608
    float* gi     = (float*)(ws + 8388608L);      // 50,331,648
    u16*   hst    = (u16*)  (ws + 58720256L);     //  8,519,680  (65x64x1024 bf16)
    u16*   Wih_b  = (u16*)  (ws + 67239936L);     //  6,291,456
    u16*   Whh_b  = (u16*)  (ws + 73531392L);     //  6,291,456
    u16*   Wout_b = (u16*)  (ws + 79822848L);     // 65,536,000
    int*   bar    = (int*)  (ws + 145358848L);    // 64 B

    hipMemsetAsync(bar, 0, 64, stream);

    long n1 = (long)G3 * DIN;          // 3,145,728
    long n2 = (long)Vsz * DDsz;        // 32,768,000
    f32_to_bf16<<<(unsigned)(n1 / 4 / 256), 256, 0, stream>>>(W_ih, Wih_b, n1);
    f32_to_bf16<<<(unsigned)(n1 / 4 / 256), 256, 0, stream>>>(W_hh, Whh_b, n1);
    f32_to_bf16<<<(unsigned)(n2 / 4 / 256), 256, 0, stream>>>(W_out, Wout_b, n2);

    build_x<<<Bsz * Tsz, 128, 0, stream>>>(emb, ctx, labels, bos, Xbf);
    init_h<<<(Bsz * DDsz) / 256, 256, 0, stream>>>(initp, hst);

    // gi = X @ W_ih^T + b_ih   (4096 x 3072), grid 768 (%8==0)
    gemm128<false><<<(4096 / 128) * (G3 / 128), 256, 0, stream>>>(
        Xbf, Wih_b, b_ih, gi, G3, DIN, 4096 / 128);

    // 64 recurrent steps in ONE persistent launch
    gru_persist<<<DDsz / 16, 128, 0, stream>>>(Whh_b, b_hh, gi, initp, hst, bar);

    // logits = states @ W_out^T + b_out -> out[b][t][v], grid 8000 (%8==0)
    gemm128<true><<<(4096 / 128) * (Vsz / 128), 256, 0, stream>>>(
        hst + (long)Bsz * DDsz, Wout_b, b_out, out, Vsz, DDsz, 4096 / 128);
}

// Round 3
// 1352.622 us; speedup vs baseline: 1.8757x; 1.2376x over previous
//
#include <hip/hip_runtime.h>

// ---- sizes (fixed by the problem) ----
#define Bsz 64
#define Tsz 64
#define Vsz 32000
#define DEsz 512
#define DDsz 1024
#define DCsz 512
#define DIN 1024     // DE+DC
#define G3 3072      // 3*DD

typedef unsigned short u16;
typedef __attribute__((ext_vector_type(8))) __bf16 bf16x8;
typedef __attribute__((ext_vector_type(4))) float f32x4;

__device__ __forceinline__ u16 f2bf(float f) {
    union { float f; unsigned int u; } v; v.f = f;
    unsigned int r = v.u + 0x7fffu + ((v.u >> 16) & 1u);  // RNE
    return (u16)(r >> 16);
}

__device__ __forceinline__ void gload_lds16(const u16* g, u16* l) {
    __builtin_amdgcn_global_load_lds(
        (const __attribute__((address_space(1))) void*)g,
        (__attribute__((address_space(3))) void*)l, 16, 0, 0);
}

// ---------- f32 -> bf16 bulk convert ----------
__global__ void f32_to_bf16(const float* __restrict__ src, u16* __restrict__ dst, long n) {
    long i = ((long)blockIdx.x * blockDim.x + threadIdx.x) * 4;
    if (i + 3 < n) {
        float4 v = *(const float4*)&src[i];
        dst[i + 0] = f2bf(v.x);
        dst[i + 1] = f2bf(v.y);
        dst[i + 2] = f2bf(v.z);
        dst[i + 3] = f2bf(v.w);
    }
}

// ---------- build X = concat(emb[token], context) as bf16, row = t*B + b ----------
__global__ void build_x(const float* __restrict__ emb, const float* __restrict__ ctx,
                        const int* __restrict__ labels, const int* __restrict__ bos,
                        u16* __restrict__ X) {
    int i = blockIdx.x;            // 0..4095
    int t = i >> 6;
    int b = i & 63;
    int tok = (t == 0) ? *bos : labels[b * Tsz + (t - 1)];
    const float* s0 = emb + (long)tok * DEsz;
    const float* s1 = ctx + (long)b * DCsz;
    u16* dst = X + (long)i * DIN;
    for (int c = threadIdx.x; c < DEsz; c += blockDim.x) {
        dst[c]        = f2bf(s0[c]);
        dst[DEsz + c] = f2bf(s1[c]);
    }
}

// ---------- h0 = broadcast(init) bf16 ----------
__global__ void init_h(const float* __restrict__ init, u16* __restrict__ hbf) {
    int c = blockIdx.x * blockDim.x + threadIdx.x;   // 0..65535
    hbf[c] = f2bf(init[c & (DDsz - 1)]);
}

// ---------- 128x128 m97-style GEMM: C = A . B^T + bias ----------
template<bool TRANS_OUT>
__global__ __launch_bounds__(256) void gemm128(
    const u16* __restrict__ A, const u16* __restrict__ Bm,
    const float* __restrict__ bias, float* __restrict__ C,
    int N, int K, int mblk)
{
    __shared__ __align__(16) u16 As[128 * 32];
    __shared__ __align__(16) u16 Bs[128 * 32];
    const int tid  = threadIdx.x;
    const int wave = tid >> 6;
    const int lane = tid & 63;
    const int wm = wave >> 1, wn = wave & 1;

    int nwg = gridDim.x;
    int wg  = blockIdx.x;
    int cpx = nwg >> 3;                      // nwg % 8 == 0 by construction
    wg = (wg & 7) * cpx + (wg >> 3);         // XCD-aware swizzle (bijective)
    const int bm = (wg % mblk) * 128;        // bm fastest -> consecutive wgs share B panel
    const int bn = (wg / mblk) * 128;

    const int sr = tid >> 2;
    const int sc = (tid & 3) * 8;
    const u16* ga0 = A  + (long)(bm + sr) * K + sc;
    const u16* ga1 = A  + (long)(bm + 64 + sr) * K + sc;
    const u16* gb0 = Bm + (long)(bn + sr) * K + sc;
    const u16* gb1 = Bm + (long)(bn + 64 + sr) * K + sc;
    u16* la0 = As + tid * 8;
    u16* la1 = As + 2048 + tid * 8;
    u16* lb0 = Bs + tid * 8;
    u16* lb1 = Bs + 2048 + tid * 8;

    const int fr = lane & 15;
    const int kh = (lane >> 4) * 8;

    f32x4 acc[4][4];
    #pragma unroll
    for (int i = 0; i < 4; ++i)
        #pragma unroll
        for (int j = 0; j < 4; ++j) acc[i][j] = f32x4{0.f, 0.f, 0.f, 0.f};

    for (int k0 = 0; k0 < K; k0 += 32) {
        gload_lds16(ga0 + k0, la0);
        gload_lds16(ga1 + k0, la1);
        gload_lds16(gb0 + k0, lb0);
        gload_lds16(gb1 + k0, lb1);
        __syncthreads();
        bf16x8 af[4], bf[4];
        #pragma unroll
        for (int mi = 0; mi < 4; ++mi)
            af[mi] = *(const bf16x8*)&As[(wm * 64 + mi * 16 + fr) * 32 + kh];
        #pragma unroll
        for (int ni = 0; ni < 4; ++ni)
            bf[ni] = *(const bf16x8*)&Bs[(wn * 64 + ni * 16 + fr) * 32 + kh];
        #pragma unroll
        for (int mi = 0; mi < 4; ++mi)
            #pragma unroll
            for (int ni = 0; ni < 4; ++ni)
                acc[mi][ni] = __builtin_amdgcn_mfma_f32_16x16x32_bf16(af[mi], bf[ni], acc[mi][ni], 0, 0, 0);
        __syncthreads();
    }

    const int r0 = (lane >> 4) * 4;
    #pragma unroll
    for (int mi = 0; mi < 4; ++mi) {
        #pragma unroll
        for (int ni = 0; ni < 4; ++ni) {
            int col = bn + wn * 64 + ni * 16 + fr;
            float bv = bias[col];
            #pragma unroll
            for (int j = 0; j < 4; ++j) {
                int row = bm + wm * 64 + mi * 16 + r0 + j;
                long oi;
                if (TRANS_OUT) {
                    oi = ((long)(row & 63) * Tsz + (row >> 6)) * (long)N + col;  // out[b][t][v]
                } else {
                    oi = (long)row * N + col;
                }
                C[oi] = acc[mi][ni][j] + bv;
            }
        }
    }
}

// ---------- persistent GRU: all 64 steps in one launch ----------
// 64 blocks x 128 thr (2 waves). Block owns 16 hidden cols x 3 gates.
// Barrier: 8 padded monotonic counters, every block polls the sum (2 L3 RTs).
#define PF 8
__global__ __launch_bounds__(128) void gru_persist(
    const u16* __restrict__ Whh,     // [3072][1024] bf16
    const float* __restrict__ bhh,   // [3072]
    const float* __restrict__ gi,    // [4096][3072] f32
    const float* __restrict__ initp, // [1024]
    u16* __restrict__ hst,           // [65][64][1024] bf16
    int* __restrict__ bar)           // 8 counters spaced 64B, zeroed
{
    __shared__ __align__(16) u16 Wl[48 * 1032];   // +8 pad
    const int tid  = threadIdx.x;
    const int w    = tid >> 6;       // wave 0/1 -> batch half
    const int lane = tid & 63;
    const int c0   = blockIdx.x * 16;
    const int fr   = lane & 15;
    const int kh   = (lane >> 4) * 8;
    const int r0   = (lane >> 4) * 4;

    // preload W slice: LDS row g*16+i <- Whh[g*1024 + c0 + i]
    for (int ch = tid; ch < 48 * 128; ch += 128) {
        int r  = ch >> 7;
        int cc = (ch & 127) * 8;
        int g  = r >> 4, i = r & 15;
        *(bf16x8*)&Wl[r * 1032 + cc] =
            *(const bf16x8*)&Whh[((long)g * DDsz + c0 + i) * DDsz + cc];
    }
    __syncthreads();

    float hc[2][4];
    {
        float v = initp[c0 + fr];
        #pragma unroll
        for (int mt = 0; mt < 2; ++mt)
            #pragma unroll
            for (int j = 0; j < 4; ++j) hc[mt][j] = v;
    }
    const float bR = bhh[c0 + fr];
    const float bZ = bhh[DDsz + c0 + fr];
    const float bN = bhh[2 * DDsz + c0 + fr];

    // gi(0) prefetch
    float gir[2][4], giz[2][4], gin_[2][4];
    #pragma unroll
    for (int mt = 0; mt < 2; ++mt)
        #pragma unroll
        for (int j = 0; j < 4; ++j) {
            long gib = ((long)(w * 32 + mt * 16 + r0 + j)) * G3 + c0 + fr;
            gir[mt][j]  = gi[gib];
            giz[mt][j]  = gi[gib + DDsz];
            gin_[mt][j] = gi[gib + 2 * DDsz];
        }

    for (int t = 0; t < Tsz; ++t) {
        const u16* hrow = hst + (long)t * (Bsz * DDsz);
        const u16* hr0 = hrow + (w * 32 + fr) * DDsz + kh;
        const u16* hr1 = hrow + (w * 32 + 16 + fr) * DDsz + kh;

        // prefetch depth PF
        bf16x8 pa0[PF], pa1[PF];
        #pragma unroll
        for (int p = 0; p < PF; ++p) {
            pa0[p] = *(const bf16x8*)(hr0 + p * 32);
            pa1[p] = *(const bf16x8*)(hr1 + p * 32);
        }

        f32x4 acc[3][2];
        #pragma unroll
        for (int g = 0; g < 3; ++g)
            #pragma unroll
            for (int mt = 0; mt < 2; ++mt) acc[g][mt] = f32x4{0.f, 0.f, 0.f, 0.f};

        #pragma unroll
        for (int k = 0; k < 32; ++k) {
            bf16x8 a0 = pa0[k & (PF - 1)];
            bf16x8 a1 = pa1[k & (PF - 1)];
            if (k < 32 - PF) {
                pa0[k & (PF - 1)] = *(const bf16x8*)(hr0 + (k + PF) * 32);
                pa1[k & (PF - 1)] = *(const bf16x8*)(hr1 + (k + PF) * 32);
            }
            bf16x8 wr_ = *(const bf16x8*)&Wl[(0  + fr) * 1032 + k * 32 + kh];
            bf16x8 wz_ = *(const bf16x8*)&Wl[(16 + fr) * 1032 + k * 32 + kh];
            bf16x8 wn_ = *(const bf16x8*)&Wl[(32 + fr) * 1032 + k * 32 + kh];
            acc[0][0] = __builtin_amdgcn_mfma_f32_16x16x32_bf16(a0, wr_, acc[0][0], 0, 0, 0);
            acc[0][1] = __builtin_amdgcn_mfma_f32_16x16x32_bf16(a1, wr_, acc[0][1], 0, 0, 0);
            acc[1][0] = __builtin_amdgcn_mfma_f32_16x16x32_bf16(a0, wz_, acc[1][0], 0, 0, 0);
            acc[1][1] = __builtin_amdgcn_mfma_f32_16x16x32_bf16(a1, wz_, acc[1][1], 0, 0, 0);
            acc[2][0] = __builtin_amdgcn_mfma_f32_16x16x32_bf16(a0, wn_, acc[2][0], 0, 0, 0);
            acc[2][1] = __builtin_amdgcn_mfma_f32_16x16x32_bf16(a1, wn_, acc[2][1], 0, 0, 0);
        }

        // gates + h store
        u16* hout = hst + (long)(t + 1) * (Bsz * DDsz);
        #pragma unroll
        for (int mt = 0; mt < 2; ++mt) {
            int bb = w * 32 + mt * 16 + r0;
            #pragma unroll
            for (int j = 0; j < 4; ++j) {
                float r = 1.f / (1.f + expf(-(gir[mt][j] + acc[0][mt][j] + bR)));
                float z = 1.f / (1.f + expf(-(giz[mt][j] + acc[1][mt][j] + bZ)));
                float n = tanhf(gin_[mt][j] + r * (acc[2][mt][j] + bN));
                float h = (1.f - z) * n + z * hc[mt][j];
                hc[mt][j] = h;
                hout[(long)(bb + j) * DDsz + c0 + fr] = f2bf(h);
            }
        }

        // issue gi(t+1) loads BEFORE the barrier: latency overlaps store-drain + barrier
        int tp = (t + 1) & 63;   // t=63 reads t=0's gi (unused) to stay in-bounds
        #pragma unroll
        for (int mt = 0; mt < 2; ++mt)
            #pragma unroll
            for (int j = 0; j < 4; ++j) {
                long gib = ((long)tp * Bsz + w * 32 + mt * 16 + r0 + j) * G3 + c0 + fr;
                gir[mt][j]  = gi[gib];
                giz[mt][j]  = gi[gib + DDsz];
                gin_[mt][j] = gi[gib + 2 * DDsz];
            }

        __syncthreads();                       // drains all waves' stores + gi loads
        if (tid == 0) {
            __builtin_amdgcn_fence(__ATOMIC_RELEASE, "agent");   // wbl2: h -> L3
            __hip_atomic_fetch_add(&bar[(blockIdx.x & 7) << 4], 1,
                                   __ATOMIC_RELAXED, __HIP_MEMORY_SCOPE_AGENT);
            const int tgt = 64 * (t + 1);
            for (;;) {
                int s = 0;
                #pragma unroll
                for (int g = 0; g < 8; ++g)
                    s += __hip_atomic_load(&bar[g << 4], __ATOMIC_RELAXED,
                                           __HIP_MEMORY_SCOPE_AGENT);
                if (s >= tgt) break;
            }
            __builtin_amdgcn_fence(__ATOMIC_ACQUIRE, "agent");   // inv L2
        }
        __syncthreads();
    }
}

extern "C" void kernel_launch(void* const* d_in, const int* in_sizes, int n_in,
                              void* d_out, int out_size, void* d_ws, size_t ws_size,
                              hipStream_t stream) {
    const float* ctx    = (const float*)d_in[0];
    const int*   labels = (const int*)  d_in[1];
    const float* emb    = (const float*)d_in[2];
    const float* W_ih   = (const float*)d_in[3];
    const float* b_ih   = (const float*)d_in[4];
    const float* W_hh   = (const float*)d_in[5];
    const float* b_hh   = (const float*)d_in[6];
    const float* initp  = (const float*)d_in[7];
    const float* W_out  = (const float*)d_in[8];
    const float* b_out  = (const float*)d_in[9];
    const int*   bos    = (const int*)  d_in[10];
    float* out = (float*)d_out;

    char* ws = (char*)d_ws;
    u16*   Xbf    = (u16*)  (ws + 0L);            //  8,388,608
    float* gi     = (float*)(ws + 8388608L);      // 50,331,648
    u16*   hst    = (u16*)  (ws + 58720256L);     //  8,519,680  (65x64x1024 bf16)
    u16*   Wih_b  = (u16*)  (ws + 67239936L);     //  6,291,456
    u16*   Whh_b  = (u16*)  (ws + 73531392L);     //  6,291,456
    u16*   Wout_b = (u16*)  (ws + 79822848L);     // 65,536,000
    int*   bar    = (int*)  (ws + 145358848L);    // 8 x 64B counters

    hipMemsetAsync(bar, 0, 1024, stream);

    long n1 = (long)G3 * DIN;          // 3,145,728
    long n2 = (long)Vsz * DDsz;        // 32,768,000
    f32_to_bf16<<<(unsigned)(n1 / 4 / 256), 256, 0, stream>>>(W_ih, Wih_b, n1);
    f32_to_bf16<<<(unsigned)(n1 / 4 / 256), 256, 0, stream>>>(W_hh, Whh_b, n1);
    f32_to_bf16<<<(unsigned)(n2 / 4 / 256), 256, 0, stream>>>(W_out, Wout_b, n2);

    build_x<<<Bsz * Tsz, 128, 0, stream>>>(emb, ctx, labels, bos, Xbf);
    init_h<<<(Bsz * DDsz) / 256, 256, 0, stream>>>(initp, hst);

    // gi = X @ W_ih^T + b_ih   (4096 x 3072), grid 768 (%8==0)
    gemm128<false><<<(4096 / 128) * (G3 / 128), 256, 0, stream>>>(
        Xbf, Wih_b, b_ih, gi, G3, DIN, 4096 / 128);

    // 64 recurrent steps in ONE persistent launch
    gru_persist<<<DDsz / 16, 128, 0, stream>>>(Whh_b, b_hh, gi, initp, hst, bar);

    // logits = states @ W_out^T + b_out -> out[b][t][v], grid 8000 (%8==0)
    gemm128<true><<<(4096 / 128) * (Vsz / 128), 256, 0, stream>>>(
        hst + (long)Bsz * DDsz, Wout_b, b_out, out, Vsz, DDsz, 4096 / 128);
}

// Round 5
// 1276.842 us; speedup vs baseline: 1.9870x; 1.0593x over previous
//
#include <hip/hip_runtime.h>

// ---- sizes (fixed by the problem) ----
#define Bsz 64
#define Tsz 64
#define Vsz 32000
#define DEsz 512
#define DDsz 1024
#define DCsz 512
#define DIN 1024     // DE+DC
#define G3 3072      // 3*DD

typedef unsigned short u16;
typedef unsigned int   u32;
typedef unsigned long long u64;
typedef __attribute__((ext_vector_type(8))) __bf16 bf16x8;
typedef __attribute__((ext_vector_type(4))) float f32x4;

__device__ __forceinline__ u16 f2bf(float f) {
    union { float f; unsigned int u; } v; v.f = f;
    unsigned int r = v.u + 0x7fffu + ((v.u >> 16) & 1u);  // RNE
    return (u16)(r >> 16);
}

__device__ __forceinline__ void gload_lds16(const u16* g, u16* l) {
    __builtin_amdgcn_global_load_lds(
        (const __attribute__((address_space(1))) void*)g,
        (__attribute__((address_space(3))) void*)l, 16, 0, 0);
}

// ---------- f32 -> bf16 bulk convert ----------
__global__ void f32_to_bf16(const float* __restrict__ src, u16* __restrict__ dst, long n) {
    long i = ((long)blockIdx.x * blockDim.x + threadIdx.x) * 4;
    if (i + 3 < n) {
        float4 v = *(const float4*)&src[i];
        dst[i + 0] = f2bf(v.x);
        dst[i + 1] = f2bf(v.y);
        dst[i + 2] = f2bf(v.z);
        dst[i + 3] = f2bf(v.w);
    }
}

// ---------- build X = concat(emb[token], context) as bf16, row = t*B + b ----------
__global__ void build_x(const float* __restrict__ emb, const float* __restrict__ ctx,
                        const int* __restrict__ labels, const int* __restrict__ bos,
                        u16* __restrict__ X) {
    int i = blockIdx.x;            // 0..4095
    int t = i >> 6;
    int b = i & 63;
    int tok = (t == 0) ? *bos : labels[b * Tsz + (t - 1)];
    const float* s0 = emb + (long)tok * DEsz;
    const float* s1 = ctx + (long)b * DCsz;
    u16* dst = X + (long)i * DIN;
    for (int c = threadIdx.x; c < DEsz; c += blockDim.x) {
        dst[c]        = f2bf(s0[c]);
        dst[DEsz + c] = f2bf(s1[c]);
    }
}

// ---------- 128x128 m97-style GEMM: C = A . B^T + bias ----------
template<bool TRANS_OUT>
__global__ __launch_bounds__(256) void gemm128(
    const u16* __restrict__ A, const u16* __restrict__ Bm,
    const float* __restrict__ bias, float* __restrict__ C,
    int N, int K, int mblk)
{
    __shared__ __align__(16) u16 As[128 * 32];
    __shared__ __align__(16) u16 Bs[128 * 32];
    const int tid  = threadIdx.x;
    const int wave = tid >> 6;
    const int lane = tid & 63;
    const int wm = wave >> 1, wn = wave & 1;

    int nwg = gridDim.x;
    int wg  = blockIdx.x;
    int cpx = nwg >> 3;                      // nwg % 8 == 0 by construction
    wg = (wg & 7) * cpx + (wg >> 3);         // XCD-aware swizzle (bijective)
    const int bm = (wg % mblk) * 128;        // bm fastest -> consecutive wgs share B panel
    const int bn = (wg / mblk) * 128;

    const int sr = tid >> 2;
    const int sc = (tid & 3) * 8;
    const u16* ga0 = A  + (long)(bm + sr) * K + sc;
    const u16* ga1 = A  + (long)(bm + 64 + sr) * K + sc;
    const u16* gb0 = Bm + (long)(bn + sr) * K + sc;
    const u16* gb1 = Bm + (long)(bn + 64 + sr) * K + sc;
    u16* la0 = As + tid * 8;
    u16* la1 = As + 2048 + tid * 8;
    u16* lb0 = Bs + tid * 8;
    u16* lb1 = Bs + 2048 + tid * 8;

    const int fr = lane & 15;
    const int kh = (lane >> 4) * 8;

    f32x4 acc[4][4];
    #pragma unroll
    for (int i = 0; i < 4; ++i)
        #pragma unroll
        for (int j = 0; j < 4; ++j) acc[i][j] = f32x4{0.f, 0.f, 0.f, 0.f};

    for (int k0 = 0; k0 < K; k0 += 32) {
        gload_lds16(ga0 + k0, la0);
        gload_lds16(ga1 + k0, la1);
        gload_lds16(gb0 + k0, lb0);
        gload_lds16(gb1 + k0, lb1);
        __syncthreads();
        bf16x8 af[4], bf[4];
        #pragma unroll
        for (int mi = 0; mi < 4; ++mi)
            af[mi] = *(const bf16x8*)&As[(wm * 64 + mi * 16 + fr) * 32 + kh];
        #pragma unroll
        for (int ni = 0; ni < 4; ++ni)
            bf[ni] = *(const bf16x8*)&Bs[(wn * 64 + ni * 16 + fr) * 32 + kh];
        #pragma unroll
        for (int mi = 0; mi < 4; ++mi)
            #pragma unroll
            for (int ni = 0; ni < 4; ++ni)
                acc[mi][ni] = __builtin_amdgcn_mfma_f32_16x16x32_bf16(af[mi], bf[ni], acc[mi][ni], 0, 0, 0);
        __syncthreads();
    }

    const int r0 = (lane >> 4) * 4;
    #pragma unroll
    for (int mi = 0; mi < 4; ++mi) {
        #pragma unroll
        for (int ni = 0; ni < 4; ++ni) {
            int col = bn + wn * 64 + ni * 16 + fr;
            float bv = bias[col];
            #pragma unroll
            for (int j = 0; j < 4; ++j) {
                int row = bm + wm * 64 + mi * 16 + r0 + j;
                long oi;
                if (TRANS_OUT) {
                    oi = ((long)(row & 63) * Tsz + (row >> 6)) * (long)N + col;  // out[b][t][v]
                } else {
                    oi = (long)row * N + col;
                }
                C[oi] = acc[mi][ni][j] + bv;
            }
        }
    }
}

// ---------- persistent GRU v3b: fence-free coherence via agent-scope (sc1) atomics ----------
// 64 blocks x 128 thr (2 waves). Block owns 16 hidden cols x 3 gates.
// h stores: packed-u32 agent-scope relaxed atomics (visible at mall on retire).
// h loads : u64 agent-scope relaxed atomics (read the mall, bypass stale XCD L2s).
// Barrier : waitcnt+syncthreads (drain stores) -> relaxed add -> poll 8 counters.
// BUGFIX vs r4: k-step fragment = 2 u64 at u64-index k*8 (was k*4 -- wrong data).
#define PF 8
__global__ __launch_bounds__(128) void gru_persist(
    const u16* __restrict__ Whh,     // [3072][1024] bf16
    const float* __restrict__ bhh,   // [3072]
    const float* __restrict__ gi,    // [4096][3072] f32
    const float* __restrict__ initp, // [1024]
    u16* __restrict__ hst,           // [65][64][1024] bf16 (slot 0 unused)
    int* __restrict__ bar)           // 8 counters spaced 64B, zeroed
{
    __shared__ __align__(16) u16 Wl[48 * 1032];   // +8 pad
    __shared__ __align__(16) u16 h0l[1024];
    const int tid  = threadIdx.x;
    const int w    = tid >> 6;       // wave 0/1 -> batch half
    const int lane = tid & 63;
    const int c0   = blockIdx.x * 16;
    const int fr   = lane & 15;
    const int kh   = (lane >> 4) * 8;
    const int r0   = (lane >> 4) * 4;

    // preload W slice: LDS row g*16+i <- Whh[g*1024 + c0 + i]
    for (int ch = tid; ch < 48 * 128; ch += 128) {
        int r  = ch >> 7;
        int cc = (ch & 127) * 8;
        int g  = r >> 4, i = r & 15;
        *(bf16x8*)&Wl[r * 1032 + cc] =
            *(const bf16x8*)&Whh[((long)g * DDsz + c0 + i) * DDsz + cc];
    }
    // h0 = bf16(init), broadcast source for t=0
    #pragma unroll
    for (int i = 0; i < 8; ++i) h0l[tid * 8 + i] = f2bf(initp[tid * 8 + i]);
    __syncthreads();

    float hc[2][4];
    {
        float v = initp[c0 + fr];
        #pragma unroll
        for (int mt = 0; mt < 2; ++mt)
            #pragma unroll
            for (int j = 0; j < 4; ++j) hc[mt][j] = v;
    }
    const float bR = bhh[c0 + fr];
    const float bZ = bhh[DDsz + c0 + fr];
    const float bN = bhh[2 * DDsz + c0 + fr];

    // gi(0) prefetch
    float gir[2][4], giz[2][4], gin_[2][4];
    #pragma unroll
    for (int mt = 0; mt < 2; ++mt)
        #pragma unroll
        for (int j = 0; j < 4; ++j) {
            long gib = ((long)(w * 32 + mt * 16 + r0 + j)) * G3 + c0 + fr;
            gir[mt][j]  = gi[gib];
            giz[mt][j]  = gi[gib + DDsz];
            gin_[mt][j] = gi[gib + 2 * DDsz];
        }

    for (int t = 0; t < Tsz; ++t) {
        f32x4 acc[3][2];
        #pragma unroll
        for (int g = 0; g < 3; ++g)
            #pragma unroll
            for (int mt = 0; mt < 2; ++mt) acc[g][mt] = f32x4{0.f, 0.f, 0.f, 0.f};

        auto mfma6 = [&](bf16x8 a0, bf16x8 a1, int k) {
            bf16x8 wr_ = *(const bf16x8*)&Wl[(0  + fr) * 1032 + k * 32 + kh];
            bf16x8 wz_ = *(const bf16x8*)&Wl[(16 + fr) * 1032 + k * 32 + kh];
            bf16x8 wn_ = *(const bf16x8*)&Wl[(32 + fr) * 1032 + k * 32 + kh];
            acc[0][0] = __builtin_amdgcn_mfma_f32_16x16x32_bf16(a0, wr_, acc[0][0], 0, 0, 0);
            acc[0][1] = __builtin_amdgcn_mfma_f32_16x16x32_bf16(a1, wr_, acc[0][1], 0, 0, 0);
            acc[1][0] = __builtin_amdgcn_mfma_f32_16x16x32_bf16(a0, wz_, acc[1][0], 0, 0, 0);
            acc[1][1] = __builtin_amdgcn_mfma_f32_16x16x32_bf16(a1, wz_, acc[1][1], 0, 0, 0);
            acc[2][0] = __builtin_amdgcn_mfma_f32_16x16x32_bf16(a0, wn_, acc[2][0], 0, 0, 0);
            acc[2][1] = __builtin_amdgcn_mfma_f32_16x16x32_bf16(a1, wn_, acc[2][1], 0, 0, 0);
        };

        if (t == 0) {
            #pragma unroll
            for (int k = 0; k < 32; ++k) {
                bf16x8 a = *(const bf16x8*)&h0l[k * 32 + kh];   // broadcast read
                mfma6(a, a, k);
            }
        } else {
            const u16* hrow = hst + (long)t * (Bsz * DDsz);
            // fragment for k-step k: 16B at element offset k*32 (+kh folded in base)
            // = u64 indices k*8 and k*8+1
            const u64* q0 = (const u64*)(hrow + (w * 32 + fr) * DDsz + kh);
            const u64* q1 = (const u64*)(hrow + (w * 32 + 16 + fr) * DDsz + kh);
            u64 p0[PF][2], p1[PF][2];
            #pragma unroll
            for (int p = 0; p < PF; ++p) {
                p0[p][0] = __hip_atomic_load(q0 + p * 8,     __ATOMIC_RELAXED, __HIP_MEMORY_SCOPE_AGENT);
                p0[p][1] = __hip_atomic_load(q0 + p * 8 + 1, __ATOMIC_RELAXED, __HIP_MEMORY_SCOPE_AGENT);
                p1[p][0] = __hip_atomic_load(q1 + p * 8,     __ATOMIC_RELAXED, __HIP_MEMORY_SCOPE_AGENT);
                p1[p][1] = __hip_atomic_load(q1 + p * 8 + 1, __ATOMIC_RELAXED, __HIP_MEMORY_SCOPE_AGENT);
            }
            #pragma unroll
            for (int k = 0; k < 32; ++k) {
                union { u64 q[2]; bf16x8 v; } ua, ub;
                ua.q[0] = p0[k & (PF - 1)][0]; ua.q[1] = p0[k & (PF - 1)][1];
                ub.q[0] = p1[k & (PF - 1)][0]; ub.q[1] = p1[k & (PF - 1)][1];
                if (k < 32 - PF) {
                    p0[k & (PF - 1)][0] = __hip_atomic_load(q0 + (k + PF) * 8,     __ATOMIC_RELAXED, __HIP_MEMORY_SCOPE_AGENT);
                    p0[k & (PF - 1)][1] = __hip_atomic_load(q0 + (k + PF) * 8 + 1, __ATOMIC_RELAXED, __HIP_MEMORY_SCOPE_AGENT);
                    p1[k & (PF - 1)][0] = __hip_atomic_load(q1 + (k + PF) * 8,     __ATOMIC_RELAXED, __HIP_MEMORY_SCOPE_AGENT);
                    p1[k & (PF - 1)][1] = __hip_atomic_load(q1 + (k + PF) * 8 + 1, __ATOMIC_RELAXED, __HIP_MEMORY_SCOPE_AGENT);
                }
                mfma6(ua.v, ub.v, k);
            }
        }

        // gates + packed write-through h store
        u16* hout = hst + (long)(t + 1) * (Bsz * DDsz);
        #pragma unroll
        for (int mt = 0; mt < 2; ++mt) {
            int bb = w * 32 + mt * 16 + r0;
            #pragma unroll
            for (int j = 0; j < 4; ++j) {
                float r = 1.f / (1.f + expf(-(gir[mt][j] + acc[0][mt][j] + bR)));
                float z = 1.f / (1.f + expf(-(giz[mt][j] + acc[1][mt][j] + bZ)));
                float n = tanhf(gin_[mt][j] + r * (acc[2][mt][j] + bN));
                float h = (1.f - z) * n + z * hc[mt][j];
                hc[mt][j] = h;
                int hb = (int)f2bf(h);
                int pb = __shfl_xor(hb, 1, 64);        // partner column bits
                if (!(fr & 1)) {
                    u32 val = ((u32)pb << 16) | (u32)hb;
                    __hip_atomic_store((u32*)(hout + (long)(bb + j) * DDsz + c0 + fr), val,
                                       __ATOMIC_RELAXED, __HIP_MEMORY_SCOPE_AGENT);
                }
            }
        }

        if (t != Tsz - 1) {
            // gi(t+1) loads: latency overlaps the store drain + barrier
            int tp = t + 1;
            #pragma unroll
            for (int mt = 0; mt < 2; ++mt)
                #pragma unroll
                for (int j = 0; j < 4; ++j) {
                    long gib = ((long)tp * Bsz + w * 32 + mt * 16 + r0 + j) * G3 + c0 + fr;
                    gir[mt][j]  = gi[gib];
                    giz[mt][j]  = gi[gib + DDsz];
                    gin_[mt][j] = gi[gib + 2 * DDsz];
                }

            asm volatile("s_waitcnt vmcnt(0)" ::: "memory");  // h stores retired (at mall)
            __syncthreads();                                  // all waves drained
            if (tid == 0) {
                __hip_atomic_fetch_add(&bar[(blockIdx.x & 7) << 4], 1,
                                       __ATOMIC_RELAXED, __HIP_MEMORY_SCOPE_AGENT);
                const int tgt = 64 * (t + 1);
                for (;;) {
                    int s = 0;
                    #pragma unroll
                    for (int g = 0; g < 8; ++g)
                        s += __hip_atomic_load(&bar[g << 4], __ATOMIC_RELAXED,
                                               __HIP_MEMORY_SCOPE_AGENT);
                    if (s >= tgt) break;
                }
            }
            __syncthreads();
        }
    }
}

extern "C" void kernel_launch(void* const* d_in, const int* in_sizes, int n_in,
                              void* d_out, int out_size, void* d_ws, size_t ws_size,
                              hipStream_t stream) {
    const float* ctx    = (const float*)d_in[0];
    const int*   labels = (const int*)  d_in[1];
    const float* emb    = (const float*)d_in[2];
    const float* W_ih   = (const float*)d_in[3];
    const float* b_ih   = (const float*)d_in[4];
    const float* W_hh   = (const float*)d_in[5];
    const float* b_hh   = (const float*)d_in[6];
    const float* initp  = (const float*)d_in[7];
    const float* W_out  = (const float*)d_in[8];
    const float* b_out  = (const float*)d_in[9];
    const int*   bos    = (const int*)  d_in[10];
    float* out = (float*)d_out;

    char* ws = (char*)d_ws;
    u16*   Xbf    = (u16*)  (ws + 0L);            //  8,388,608
    float* gi     = (float*)(ws + 8388608L);      // 50,331,648
    u16*   hst    = (u16*)  (ws + 58720256L);     //  8,519,680  (65x64x1024 bf16)
    u16*   Wih_b  = (u16*)  (ws + 67239936L);     //  6,291,456
    u16*   Whh_b  = (u16*)  (ws + 73531392L);     //  6,291,456
    u16*   Wout_b = (u16*)  (ws + 79822848L);     // 65,536,000
    int*   bar    = (int*)  (ws + 145358848L);    // 8 x 64B counters

    hipMemsetAsync(bar, 0, 1024, stream);

    long n1 = (long)G3 * DIN;          // 3,145,728
    long n2 = (long)Vsz * DDsz;        // 32,768,000
    f32_to_bf16<<<(unsigned)(n1 / 4 / 256), 256, 0, stream>>>(W_ih, Wih_b, n1);
    f32_to_bf16<<<(unsigned)(n1 / 4 / 256), 256, 0, stream>>>(W_hh, Whh_b, n1);
    f32_to_bf16<<<(unsigned)(n2 / 4 / 256), 256, 0, stream>>>(W_out, Wout_b, n2);

    build_x<<<Bsz * Tsz, 128, 0, stream>>>(emb, ctx, labels, bos, Xbf);

    // gi = X @ W_ih^T + b_ih   (4096 x 3072), grid 768 (%8==0)
    gemm128<false><<<(4096 / 128) * (G3 / 128), 256, 0, stream>>>(
        Xbf, Wih_b, b_ih, gi, G3, DIN, 4096 / 128);

    // 64 recurrent steps in ONE persistent launch (fence-free)
    gru_persist<<<DDsz / 16, 128, 0, stream>>>(Whh_b, b_hh, gi, initp, hst, bar);

    // logits = states @ W_out^T + b_out -> out[b][t][v], grid 8000 (%8==0)
    gemm128<true><<<(4096 / 128) * (Vsz / 128), 256, 0, stream>>>(
        hst + (long)Bsz * DDsz, Wout_b, b_out, out, Vsz, DDsz, 4096 / 128);
}

// Round 6
// 1178.477 us; speedup vs baseline: 2.1529x; 1.0835x over previous
//
#include <hip/hip_runtime.h>

// ---- sizes (fixed by the problem) ----
#define Bsz 64
#define Tsz 64
#define Vsz 32000
#define DEsz 512
#define DDsz 1024
#define DCsz 512
#define DIN 1024     // DE+DC
#define G3 3072      // 3*DD

typedef unsigned short u16;
typedef unsigned int   u32;
typedef unsigned long long u64;
typedef __attribute__((ext_vector_type(8))) __bf16 bf16x8;
typedef __attribute__((ext_vector_type(4))) float f32x4;

__device__ __forceinline__ u16 f2bf(float f) {
    union { float f; unsigned int u; } v; v.f = f;
    unsigned int r = v.u + 0x7fffu + ((v.u >> 16) & 1u);  // RNE
    return (u16)(r >> 16);
}

__device__ __forceinline__ void gload_lds16(const u16* g, u16* l) {
    __builtin_amdgcn_global_load_lds(
        (const __attribute__((address_space(1))) void*)g,
        (__attribute__((address_space(3))) void*)l, 16, 0, 0);
}

__device__ __forceinline__ float fast_sigmoid(float x) {
    float xc = fminf(fmaxf(x, -30.f), 30.f);
    return 1.f / (1.f + __expf(-xc));
}
__device__ __forceinline__ float fast_tanh(float x) {
    float xc = fminf(fmaxf(x, -15.f), 15.f);
    float e = __expf(2.f * xc);
    return (e - 1.f) / (e + 1.f);
}

// ---------- f32 -> bf16 bulk convert ----------
__global__ void f32_to_bf16(const float* __restrict__ src, u16* __restrict__ dst, long n) {
    long i = ((long)blockIdx.x * blockDim.x + threadIdx.x) * 4;
    if (i + 3 < n) {
        float4 v = *(const float4*)&src[i];
        dst[i + 0] = f2bf(v.x);
        dst[i + 1] = f2bf(v.y);
        dst[i + 2] = f2bf(v.z);
        dst[i + 3] = f2bf(v.w);
    }
}

// ---------- build X = concat(emb[token], context) as bf16, row = t*B + b ----------
__global__ void build_x(const float* __restrict__ emb, const float* __restrict__ ctx,
                        const int* __restrict__ labels, const int* __restrict__ bos,
                        u16* __restrict__ X) {
    int i = blockIdx.x;            // 0..4095
    int t = i >> 6;
    int b = i & 63;
    int tok = (t == 0) ? *bos : labels[b * Tsz + (t - 1)];
    const float* s0 = emb + (long)tok * DEsz;
    const float* s1 = ctx + (long)b * DCsz;
    u16* dst = X + (long)i * DIN;
    for (int c = threadIdx.x; c < DEsz; c += blockDim.x) {
        dst[c]        = f2bf(s0[c]);
        dst[DEsz + c] = f2bf(s1[c]);
    }
}

// ---------- 128x128 m97-style GEMM: C = A . B^T + bias ----------
template<bool TRANS_OUT>
__global__ __launch_bounds__(256) void gemm128(
    const u16* __restrict__ A, const u16* __restrict__ Bm,
    const float* __restrict__ bias, float* __restrict__ C,
    int N, int K, int mblk)
{
    __shared__ __align__(16) u16 As[128 * 32];
    __shared__ __align__(16) u16 Bs[128 * 32];
    const int tid  = threadIdx.x;
    const int wave = tid >> 6;
    const int lane = tid & 63;
    const int wm = wave >> 1, wn = wave & 1;

    int nwg = gridDim.x;
    int wg  = blockIdx.x;
    int cpx = nwg >> 3;                      // nwg % 8 == 0 by construction
    wg = (wg & 7) * cpx + (wg >> 3);         // XCD-aware swizzle (bijective)
    const int bm = (wg % mblk) * 128;        // bm fastest -> consecutive wgs share B panel
    const int bn = (wg / mblk) * 128;

    const int sr = tid >> 2;
    const int sc = (tid & 3) * 8;
    const u16* ga0 = A  + (long)(bm + sr) * K + sc;
    const u16* ga1 = A  + (long)(bm + 64 + sr) * K + sc;
    const u16* gb0 = Bm + (long)(bn + sr) * K + sc;
    const u16* gb1 = Bm + (long)(bn + 64 + sr) * K + sc;
    u16* la0 = As + tid * 8;
    u16* la1 = As + 2048 + tid * 8;
    u16* lb0 = Bs + tid * 8;
    u16* lb1 = Bs + 2048 + tid * 8;

    const int fr = lane & 15;
    const int kh = (lane >> 4) * 8;

    f32x4 acc[4][4];
    #pragma unroll
    for (int i = 0; i < 4; ++i)
        #pragma unroll
        for (int j = 0; j < 4; ++j) acc[i][j] = f32x4{0.f, 0.f, 0.f, 0.f};

    for (int k0 = 0; k0 < K; k0 += 32) {
        gload_lds16(ga0 + k0, la0);
        gload_lds16(ga1 + k0, la1);
        gload_lds16(gb0 + k0, lb0);
        gload_lds16(gb1 + k0, lb1);
        __syncthreads();
        bf16x8 af[4], bf[4];
        #pragma unroll
        for (int mi = 0; mi < 4; ++mi)
            af[mi] = *(const bf16x8*)&As[(wm * 64 + mi * 16 + fr) * 32 + kh];
        #pragma unroll
        for (int ni = 0; ni < 4; ++ni)
            bf[ni] = *(const bf16x8*)&Bs[(wn * 64 + ni * 16 + fr) * 32 + kh];
        #pragma unroll
        for (int mi = 0; mi < 4; ++mi)
            #pragma unroll
            for (int ni = 0; ni < 4; ++ni)
                acc[mi][ni] = __builtin_amdgcn_mfma_f32_16x16x32_bf16(af[mi], bf[ni], acc[mi][ni], 0, 0, 0);
        __syncthreads();
    }

    const int r0 = (lane >> 4) * 4;
    #pragma unroll
    for (int mi = 0; mi < 4; ++mi) {
        #pragma unroll
        for (int ni = 0; ni < 4; ++ni) {
            int col = bn + wn * 64 + ni * 16 + fr;
            float bv = bias[col];
            #pragma unroll
            for (int j = 0; j < 4; ++j) {
                int row = bm + wm * 64 + mi * 16 + r0 + j;
                long oi;
                if (TRANS_OUT) {
                    oi = ((long)(row & 63) * Tsz + (row >> 6)) * (long)N + col;  // out[b][t][v]
                } else {
                    oi = (long)row * N + col;
                }
                C[oi] = acc[mi][ni][j] + bv;
            }
        }
    }
}

// ---------- persistent GRU v4: 4 waves/block, PF=16, fast gates ----------
// 64 blocks x 256 thr. Block owns 16 hidden cols x 3 gates; wave w owns batch
// rows [16w,16w+16). h stores: packed-u32 agent-scope relaxed atomics.
// h loads: u64 agent-scope relaxed atomics, PF=16 pipeline.
#define PF 16
__global__ __launch_bounds__(256) void gru_persist(
    const u16* __restrict__ Whh,     // [3072][1024] bf16
    const float* __restrict__ bhh,   // [3072]
    const float* __restrict__ gi,    // [4096][3072] f32
    const float* __restrict__ initp, // [1024]
    u16* __restrict__ hst,           // [65][64][1024] bf16 (slot 0 unused)
    int* __restrict__ bar)           // 8 counters spaced 64B, zeroed
{
    __shared__ __align__(16) u16 Wl[48 * 1032];   // +8 pad
    __shared__ __align__(16) u16 h0l[1024];
    const int tid  = threadIdx.x;
    const int w    = tid >> 6;       // wave 0..3 -> batch quarter
    const int lane = tid & 63;
    const int c0   = blockIdx.x * 16;
    const int fr   = lane & 15;
    const int kh   = (lane >> 4) * 8;
    const int r0   = (lane >> 4) * 4;

    // preload W slice: LDS row g*16+i <- Whh[g*1024 + c0 + i]
    for (int ch = tid; ch < 48 * 128; ch += 256) {
        int r  = ch >> 7;
        int cc = (ch & 127) * 8;
        int g  = r >> 4, i = r & 15;
        *(bf16x8*)&Wl[r * 1032 + cc] =
            *(const bf16x8*)&Whh[((long)g * DDsz + c0 + i) * DDsz + cc];
    }
    // h0 = bf16(init), broadcast source for t=0
    #pragma unroll
    for (int i = 0; i < 4; ++i) h0l[tid * 4 + i] = f2bf(initp[tid * 4 + i]);
    __syncthreads();

    float hc[4];
    {
        float v = initp[c0 + fr];
        #pragma unroll
        for (int j = 0; j < 4; ++j) hc[j] = v;
    }
    const float bR = bhh[c0 + fr];
    const float bZ = bhh[DDsz + c0 + fr];
    const float bN = bhh[2 * DDsz + c0 + fr];

    // gi(0) prefetch
    float gir[4], giz[4], gin_[4];
    #pragma unroll
    for (int j = 0; j < 4; ++j) {
        long gib = ((long)(w * 16 + r0 + j)) * G3 + c0 + fr;
        gir[j]  = gi[gib];
        giz[j]  = gi[gib + DDsz];
        gin_[j] = gi[gib + 2 * DDsz];
    }

    for (int t = 0; t < Tsz; ++t) {
        f32x4 acc[3];
        #pragma unroll
        for (int g = 0; g < 3; ++g) acc[g] = f32x4{0.f, 0.f, 0.f, 0.f};

        auto mfma3 = [&](bf16x8 a, int k) {
            bf16x8 wr_ = *(const bf16x8*)&Wl[(0  + fr) * 1032 + k * 32 + kh];
            bf16x8 wz_ = *(const bf16x8*)&Wl[(16 + fr) * 1032 + k * 32 + kh];
            bf16x8 wn_ = *(const bf16x8*)&Wl[(32 + fr) * 1032 + k * 32 + kh];
            acc[0] = __builtin_amdgcn_mfma_f32_16x16x32_bf16(a, wr_, acc[0], 0, 0, 0);
            acc[1] = __builtin_amdgcn_mfma_f32_16x16x32_bf16(a, wz_, acc[1], 0, 0, 0);
            acc[2] = __builtin_amdgcn_mfma_f32_16x16x32_bf16(a, wn_, acc[2], 0, 0, 0);
        };

        if (t == 0) {
            #pragma unroll
            for (int k = 0; k < 32; ++k) {
                bf16x8 a = *(const bf16x8*)&h0l[k * 32 + kh];   // broadcast read
                mfma3(a, k);
            }
        } else {
            const u16* hrow = hst + (long)t * (Bsz * DDsz);
            // k-step fragment = 16B at element offset k*32 => u64 indices k*8, k*8+1
            const u64* q0 = (const u64*)(hrow + (w * 16 + fr) * DDsz + kh);
            u64 p0[PF][2];
            #pragma unroll
            for (int p = 0; p < PF; ++p) {
                p0[p][0] = __hip_atomic_load(q0 + p * 8,     __ATOMIC_RELAXED, __HIP_MEMORY_SCOPE_AGENT);
                p0[p][1] = __hip_atomic_load(q0 + p * 8 + 1, __ATOMIC_RELAXED, __HIP_MEMORY_SCOPE_AGENT);
            }
            #pragma unroll
            for (int k = 0; k < 32; ++k) {
                union { u64 q[2]; bf16x8 v; } ua;
                ua.q[0] = p0[k & (PF - 1)][0];
                ua.q[1] = p0[k & (PF - 1)][1];
                if (k < 32 - PF) {
                    p0[k & (PF - 1)][0] = __hip_atomic_load(q0 + (k + PF) * 8,     __ATOMIC_RELAXED, __HIP_MEMORY_SCOPE_AGENT);
                    p0[k & (PF - 1)][1] = __hip_atomic_load(q0 + (k + PF) * 8 + 1, __ATOMIC_RELAXED, __HIP_MEMORY_SCOPE_AGENT);
                }
                mfma3(ua.v, k);
            }
        }

        // gates + packed write-through h store
        u16* hout = hst + (long)(t + 1) * (Bsz * DDsz);
        #pragma unroll
        for (int j = 0; j < 4; ++j) {
            int row = w * 16 + r0 + j;
            float r = fast_sigmoid(gir[j] + acc[0][j] + bR);
            float z = fast_sigmoid(giz[j] + acc[1][j] + bZ);
            float n = fast_tanh(gin_[j] + r * (acc[2][j] + bN));
            float h = (1.f - z) * n + z * hc[j];
            hc[j] = h;
            int hb = (int)f2bf(h);
            int pb = __shfl_xor(hb, 1, 64);        // partner column bits
            if (!(fr & 1)) {
                u32 val = ((u32)pb << 16) | (u32)hb;
                __hip_atomic_store((u32*)(hout + (long)row * DDsz + c0 + fr), val,
                                   __ATOMIC_RELAXED, __HIP_MEMORY_SCOPE_AGENT);
            }
        }

        if (t != Tsz - 1) {
            // gi(t+1) loads: HBM latency overlaps the store drain + barrier
            int tp = t + 1;
            #pragma unroll
            for (int j = 0; j < 4; ++j) {
                long gib = ((long)tp * Bsz + w * 16 + r0 + j) * G3 + c0 + fr;
                gir[j]  = gi[gib];
                giz[j]  = gi[gib + DDsz];
                gin_[j] = gi[gib + 2 * DDsz];
            }

            asm volatile("s_waitcnt vmcnt(0)" ::: "memory");  // h stores at mall
            __syncthreads();                                  // all waves drained
            if (tid == 0) {
                __hip_atomic_fetch_add(&bar[(blockIdx.x & 7) << 4], 1,
                                       __ATOMIC_RELAXED, __HIP_MEMORY_SCOPE_AGENT);
                const int tgt = 64 * (t + 1);
                for (;;) {
                    int s = 0;
                    #pragma unroll
                    for (int g = 0; g < 8; ++g)
                        s += __hip_atomic_load(&bar[g << 4], __ATOMIC_RELAXED,
                                               __HIP_MEMORY_SCOPE_AGENT);
                    if (s >= tgt) break;
                }
            }
            __syncthreads();
        }
    }
}

extern "C" void kernel_launch(void* const* d_in, const int* in_sizes, int n_in,
                              void* d_out, int out_size, void* d_ws, size_t ws_size,
                              hipStream_t stream) {
    const float* ctx    = (const float*)d_in[0];
    const int*   labels = (const int*)  d_in[1];
    const float* emb    = (const float*)d_in[2];
    const float* W_ih   = (const float*)d_in[3];
    const float* b_ih   = (const float*)d_in[4];
    const float* W_hh   = (const float*)d_in[5];
    const float* b_hh   = (const float*)d_in[6];
    const float* initp  = (const float*)d_in[7];
    const float* W_out  = (const float*)d_in[8];
    const float* b_out  = (const float*)d_in[9];
    const int*   bos    = (const int*)  d_in[10];
    float* out = (float*)d_out;

    char* ws = (char*)d_ws;
    u16*   Xbf    = (u16*)  (ws + 0L);            //  8,388,608
    float* gi     = (float*)(ws + 8388608L);      // 50,331,648
    u16*   hst    = (u16*)  (ws + 58720256L);     //  8,519,680  (65x64x1024 bf16)
    u16*   Wih_b  = (u16*)  (ws + 67239936L);     //  6,291,456
    u16*   Whh_b  = (u16*)  (ws + 73531392L);     //  6,291,456
    u16*   Wout_b = (u16*)  (ws + 79822848L);     // 65,536,000
    int*   bar    = (int*)  (ws + 145358848L);    // 8 x 64B counters

    hipMemsetAsync(bar, 0, 1024, stream);

    long n1 = (long)G3 * DIN;          // 3,145,728
    long n2 = (long)Vsz * DDsz;        // 32,768,000
    f32_to_bf16<<<(unsigned)(n1 / 4 / 256), 256, 0, stream>>>(W_ih, Wih_b, n1);
    f32_to_bf16<<<(unsigned)(n1 / 4 / 256), 256, 0, stream>>>(W_hh, Whh_b, n1);
    f32_to_bf16<<<(unsigned)(n2 / 4 / 256), 256, 0, stream>>>(W_out, Wout_b, n2);

    build_x<<<Bsz * Tsz, 128, 0, stream>>>(emb, ctx, labels, bos, Xbf);

    // gi = X @ W_ih^T + b_ih   (4096 x 3072), grid 768 (%8==0)
    gemm128<false><<<(4096 / 128) * (G3 / 128), 256, 0, stream>>>(
        Xbf, Wih_b, b_ih, gi, G3, DIN, 4096 / 128);

    // 64 recurrent steps in ONE persistent launch (fence-free)
    gru_persist<<<DDsz / 16, 256, 0, stream>>>(Whh_b, b_hh, gi, initp, hst, bar);

    // logits = states @ W_out^T + b_out -> out[b][t][v], grid 8000 (%8==0)
    gemm128<true><<<(4096 / 128) * (Vsz / 128), 256, 0, stream>>>(
        hst + (long)Bsz * DDsz, Wout_b, b_out, out, Vsz, DDsz, 4096 / 128);
}